// Round 5
// baseline (272.950 us; speedup 1.0000x reference)
//
#include <hip/hip_runtime.h>
#include <hip/hip_bf16.h>
#include <cstdint>
#include <cstddef>

#define DIM 4096
#define NB 16
#define NH 32
#define NKV 8
#define HD 128
#define PREFIX 8192
#define KPB 256                   // keys per block
#define KPW 64                    // keys per wave
#define NCH (PREFIX / KPB)        // 32 key-chunks per batch
#define NPART NCH                 // 32 merged partials per (b, head)

// workspace layout (in floats)
#define WS_QKV 0                                   // [16][6144] q|k_new|v_new
#define WS_ATT (WS_QKV + NB * 6144)                // [16][4096] attn output
#define WS_ML  (WS_ATT + NB * DIM)                 // [512 blocks][32 gh][2]
#define WS_OP  (WS_ML + NB * NCH * 32 * 2)         // [512 blocks][32 gh][128]

// ---------------------------------------------------------------------------
// Batched GEMV: Y[b][row] = sum_d X[b][d] * W[row][d], B=16, D=4096.
// W = concat of up to three row-major matrices (boundaries b1,b2).
// NW waves per block; each wave owns 4 rows x 16 batches. x staged in two
// 2048-dim chunks (128 KB LDS) -> only 2 barrier pairs per block.
// ---------------------------------------------------------------------------
template <int NW>
__global__ __launch_bounds__(NW * 64) void gemv16(
    const float* __restrict__ W0, const float* __restrict__ W1,
    const float* __restrict__ W2, int b1, int b2,
    const float* __restrict__ X, float* __restrict__ Y,
    int y_stride, int scale_rows, float scale) {
  __shared__ float xs[NB][2048];  // 128 KB
  const int tid = threadIdx.x;
  const int wave = tid >> 6, lane = tid & 63;
  const int row_base = blockIdx.x * (NW * 4) + wave * 4;

  const float* Wp;
  if (row_base < b1)       Wp = W0 + (size_t)row_base * DIM;
  else if (row_base < b2)  Wp = W1 + (size_t)(row_base - b1) * DIM;
  else                     Wp = W2 + (size_t)(row_base - b2) * DIM;

  float acc[4][NB];
#pragma unroll
  for (int r = 0; r < 4; ++r)
#pragma unroll
    for (int b = 0; b < NB; ++b) acc[r][b] = 0.0f;

  for (int k0 = 0; k0 < DIM; k0 += 2048) {
    __syncthreads();
#pragma unroll
    for (int i = 0; i < (8192 + NW * 64 - 1) / (NW * 64); ++i) {
      const int idx = tid + i * (NW * 64);
      if (idx < 8192) {
        const int b = idx >> 9, c = idx & 511;
        ((float4*)&xs[b][0])[c] =
            ((const float4*)(X + (size_t)b * DIM + k0))[c];
      }
    }
    __syncthreads();
#pragma unroll 4
    for (int ii = 0; ii < 8; ++ii) {
      const int d = ii * 256 + lane * 4;
      float4 w4[4];
#pragma unroll
      for (int r = 0; r < 4; ++r)
        w4[r] = *(const float4*)(Wp + (size_t)r * DIM + k0 + d);
#pragma unroll
      for (int b = 0; b < NB; ++b) {
        float4 x4 = *(const float4*)&xs[b][d];
#pragma unroll
        for (int r = 0; r < 4; ++r)
          acc[r][b] += w4[r].x * x4.x + w4[r].y * x4.y +
                       w4[r].z * x4.z + w4[r].w * x4.w;
      }
    }
  }

#pragma unroll
  for (int r = 0; r < 4; ++r)
#pragma unroll
    for (int b = 0; b < NB; ++b) {
      float v = acc[r][b];
#pragma unroll
      for (int m = 1; m < 64; m <<= 1) v += __shfl_xor(v, m);
      acc[r][b] = v;
    }
  const int rsel = lane >> 4, bsel = lane & 15;
  float v = 0.0f;
#pragma unroll
  for (int r = 0; r < 4; ++r)
#pragma unroll
    for (int b = 0; b < NB; ++b)
      if (r == rsel && b == bsel) v = acc[r][b];  // compile-time indices only
  const int row = row_base + rsel;
  if (row < scale_rows) v *= scale;
  Y[(size_t)bsel * y_stride + row] = v;
}

// ---------------------------------------------------------------------------
// Row-contiguous flash-decoding partial. Block = (b, 256-key range) covering
// ALL 8 kv-heads; wave owns 64 keys and streams K rows (4 KB each) fully
// sequentially: lane l -> section g=l>>3, dims (l&7)*4 + j*32. Scores for all
// 32 (g,h) pairs; wave-local softmax; PV with identical mapping; in-block
// merge of the 4 wave-partials (2 barriers). Every K/V byte is read exactly
// once, in sequential 4 KB rows -> DRAM-friendly.
// ---------------------------------------------------------------------------
__global__ __launch_bounds__(256, 2) void attn_partial(
    const float* __restrict__ K, const float* __restrict__ V,
    const float* __restrict__ qkv, float* __restrict__ opart,
    float* __restrict__ mlpart) {
  __shared__ float lds[4 * 32 * 132];  // 67.6 KB: scores, then merge buffer
  __shared__ float mw[4][32], lw[4][32];
  const int tid = threadIdx.x, wave = tid >> 6, lane = tid & 63;
  const int g = lane >> 3, soff = lane & 7;
  const int bid = blockIdx.x;
  const int c = bid & (NCH - 1), b = bid >> 5;

  float* scw = lds + wave * (KPW * 32);  // per-wave scores [64 keys][32 gh]

  // q fragments: qreg[hh][j] = q[g*4+hh][j*32 + soff*4 .. +3] (pre-scaled)
  float4 qreg[4][4];
#pragma unroll
  for (int hh = 0; hh < 4; ++hh)
#pragma unroll
    for (int j = 0; j < 4; ++j)
      qreg[hh][j] = *(const float4*)(qkv + (size_t)b * 6144 +
                                     (g * 4 + hh) * HD + j * 32 + soff * 4);

  const size_t rowbase = ((size_t)b * PREFIX + c * KPB + wave * KPW) *
                         (NKV * HD);
  const float* kp = K + rowbase + g * HD + soff * 4;

  // ---- scoring: 64 sequential 4 KB rows per wave ----
  float mreg[4] = {-1e30f, -1e30f, -1e30f, -1e30f};
#pragma unroll 2
  for (int k = 0; k < KPW; ++k) {
    float4 k4[4];
#pragma unroll
    for (int j = 0; j < 4; ++j)
      k4[j] = *(const float4*)(kp + (size_t)k * (NKV * HD) + j * 32);
    float p[4] = {0.f, 0.f, 0.f, 0.f};
#pragma unroll
    for (int j = 0; j < 4; ++j)
#pragma unroll
      for (int hh = 0; hh < 4; ++hh)
        p[hh] += qreg[hh][j].x * k4[j].x + qreg[hh][j].y * k4[j].y +
                 qreg[hh][j].z * k4[j].z + qreg[hh][j].w * k4[j].w;
    // reduce over the 8 lanes of this section (allreduce butterfly)
#pragma unroll
    for (int mk = 1; mk < 8; mk <<= 1) {
      p[0] += __shfl_xor(p[0], mk);
      p[1] += __shfl_xor(p[1], mk);
      p[2] += __shfl_xor(p[2], mk);
      p[3] += __shfl_xor(p[3], mk);
    }
#pragma unroll
    for (int hh = 0; hh < 4; ++hh) mreg[hh] = fmaxf(mreg[hh], p[hh]);
    float wv = p[0];
    wv = (soff == 1) ? p[1] : wv;
    wv = (soff == 2) ? p[2] : wv;
    wv = (soff == 3) ? p[3] : wv;
    if (soff < 4) scw[k * 32 + g * 4 + soff] = wv;  // banks distinct
  }
  {
    float mv = mreg[0];
    mv = (soff == 1) ? mreg[1] : mv;
    mv = (soff == 2) ? mreg[2] : mv;
    mv = (soff == 3) ? mreg[3] : mv;
    if (soff < 4) mw[wave][g * 4 + soff] = mv;
  }
  asm volatile("s_waitcnt lgkmcnt(0)" ::: "memory");
  __builtin_amdgcn_sched_barrier(0);

  // ---- exp pass: lane pair per gh; accumulate l ----
  {
    const int gh = lane >> 1, half = lane & 1;
    const float m = mw[wave][gh];
    float lsum = 0.f;
#pragma unroll 8
    for (int i = 0; i < 32; ++i) {
      const int idx = (half * 32 + i) * 32 + gh;
      const float pe = __expf(scw[idx] - m);
      scw[idx] = pe;
      lsum += pe;
    }
    lsum += __shfl_xor(lsum, 1);
    if (half == 0) lw[wave][gh] = lsum;
  }
  asm volatile("s_waitcnt lgkmcnt(0)" ::: "memory");
  __builtin_amdgcn_sched_barrier(0);

  // ---- PV: same contiguous mapping over V ----
  const float* vp = V + rowbase + g * HD + soff * 4;
  float4 acc[4][4];
#pragma unroll
  for (int hh = 0; hh < 4; ++hh)
#pragma unroll
    for (int j = 0; j < 4; ++j) acc[hh][j] = make_float4(0.f, 0.f, 0.f, 0.f);
#pragma unroll 2
  for (int k = 0; k < KPW; ++k) {
    float4 v4[4];
#pragma unroll
    for (int j = 0; j < 4; ++j)
      v4[j] = *(const float4*)(vp + (size_t)k * (NKV * HD) + j * 32);
    float pr[4];
#pragma unroll
    for (int hh = 0; hh < 4; ++hh) pr[hh] = scw[k * 32 + g * 4 + hh];
#pragma unroll
    for (int hh = 0; hh < 4; ++hh)
#pragma unroll
      for (int j = 0; j < 4; ++j) {
        acc[hh][j].x += pr[hh] * v4[j].x;
        acc[hh][j].y += pr[hh] * v4[j].y;
        acc[hh][j].z += pr[hh] * v4[j].z;
        acc[hh][j].w += pr[hh] * v4[j].w;
      }
  }

  // ---- in-block merge of the 4 wave-partials ----
  __syncthreads();  // all PV reads of scw done before overwrite
  float* mb = lds + wave * (32 * 132);
#pragma unroll
  for (int hh = 0; hh < 4; ++hh)
#pragma unroll
    for (int j = 0; j < 4; ++j)
      *(float4*)(mb + (g * 4 + hh) * 132 + j * 32 + soff * 4) = acc[hh][j];
  __syncthreads();
  {
    const int gh = tid >> 3, sub = tid & 7;
    const float m0 = mw[0][gh], m1 = mw[1][gh], m2 = mw[2][gh], m3 = mw[3][gh];
    const float M = fmaxf(fmaxf(m0, m1), fmaxf(m2, m3));
    const float w0 = __expf(m0 - M), w1 = __expf(m1 - M);
    const float w2 = __expf(m2 - M), w3 = __expf(m3 - M);
    const float L = w0 * lw[0][gh] + w1 * lw[1][gh] +
                    w2 * lw[2][gh] + w3 * lw[3][gh];
    const size_t obase = ((size_t)bid * 32 + gh) * HD;
#pragma unroll
    for (int i = 0; i < 4; ++i) {
      const int d = sub * 16 + i * 4;
      float4 a0 = *(const float4*)(lds + 0 * 4224 + gh * 132 + d);
      float4 a1 = *(const float4*)(lds + 1 * 4224 + gh * 132 + d);
      float4 a2 = *(const float4*)(lds + 2 * 4224 + gh * 132 + d);
      float4 a3 = *(const float4*)(lds + 3 * 4224 + gh * 132 + d);
      float4 o;
      o.x = w0 * a0.x + w1 * a1.x + w2 * a2.x + w3 * a3.x;
      o.y = w0 * a0.y + w1 * a1.y + w2 * a2.y + w3 * a3.y;
      o.z = w0 * a0.z + w1 * a1.z + w2 * a2.z + w3 * a3.z;
      o.w = w0 * a0.w + w1 * a1.w + w2 * a2.w + w3 * a3.w;
      *(float4*)(opart + obase + d) = o;
    }
    if (sub == 0)
      *(float2*)(mlpart + ((size_t)bid * 32 + gh) * 2) = make_float2(M, L);
  }
}

// ---------------------------------------------------------------------------
// Combine the 32 chunk-partials per (b, head) AND fold in the new token
// analytically (its score is a single 128-dim dot). One wave per (b,h).
// ---------------------------------------------------------------------------
__global__ __launch_bounds__(64) void combine(
    const float* __restrict__ opart, const float* __restrict__ mlpart,
    const float* __restrict__ qkv, float* __restrict__ aout) {
  const int bh = blockIdx.x;  // b*32 + hg
  const int hg = bh & 31, b = bh >> 5;
  const int g = hg >> 2;
  const int lane = threadIdx.x;

  // new-token score: q (already scaled) . k_new
  const float* qp = qkv + (size_t)b * 6144 + hg * HD;
  const float* kn = qkv + (size_t)b * 6144 + 4096 + g * HD;
  const float* vn = qkv + (size_t)b * 6144 + 5120 + g * HD;
  float2 q2 = *(const float2*)(qp + lane * 2);
  float2 k2 = *(const float2*)(kn + lane * 2);
  float sn = q2.x * k2.x + q2.y * k2.y;
#pragma unroll
  for (int mk = 1; mk < 64; mk <<= 1) sn += __shfl_xor(sn, mk);

  float M = sn;
#pragma unroll 8
  for (int c = 0; c < NPART; ++c)
    M = fmaxf(M, mlpart[((size_t)(b * NCH + c) * 32 + hg) * 2]);

  float L = 0, ax = 0, ay = 0;
#pragma unroll 8
  for (int c = 0; c < NPART; ++c) {
    const size_t pidx = (size_t)(b * NCH + c) * 32 + hg;
    const float mc = mlpart[pidx * 2 + 0];
    const float lc = mlpart[pidx * 2 + 1];
    const float w = __expf(mc - M);
    L += lc * w;
    float2 o2 = *(const float2*)(opart + pidx * HD + lane * 2);
    ax += w * o2.x;
    ay += w * o2.y;
  }
  const float pn = __expf(sn - M);
  float2 v2 = *(const float2*)(vn + lane * 2);
  L += pn;
  ax += pn * v2.x;
  ay += pn * v2.y;

  const float inv = 1.0f / L;
  aout[(size_t)b * DIM + hg * HD + lane * 2 + 0] = ax * inv;
  aout[(size_t)b * DIM + hg * HD + lane * 2 + 1] = ay * inv;
}

// ---------------------------------------------------------------------------
extern "C" void kernel_launch(void* const* d_in, const int* in_sizes, int n_in,
                              void* d_out, int out_size, void* d_ws,
                              size_t ws_size, hipStream_t stream) {
  const float* x  = (const float*)d_in[0];
  const float* ck = (const float*)d_in[1];
  const float* cv = (const float*)d_in[2];
  const float* wq = (const float*)d_in[3];
  const float* wk = (const float*)d_in[4];
  const float* wv = (const float*)d_in[5];
  const float* wo = (const float*)d_in[6];
  float* out = (float*)d_out;
  float* ws = (float*)d_ws;

  float* qkv = ws + WS_QKV;
  float* att = ws + WS_ATT;
  float* ml  = ws + WS_ML;
  float* op  = ws + WS_OP;

  const float scale = 0.08838834764831845f;  // 1/sqrt(128)

  // 1) fused q/k_new/v_new projection: 6144 rows = 24 rows x 256 blocks
  gemv16<6><<<256, 384, 0, stream>>>(wq, wk, wv, 4096, 5120, x, qkv, 6144,
                                     4096, scale);
  // 2) row-contiguous flash partials: 512 blocks (2/CU), all heads per block
  attn_partial<<<NB * NCH, 256, 0, stream>>>(ck, cv, qkv, op, ml);
  // 3) merge 32 partials per (b,h) + new token
  combine<<<NB * NH, 64, 0, stream>>>(op, ml, qkv, att);
  // 4) output projection: 4096 rows = 16 rows x 256 blocks
  gemv16<4><<<256, 256, 0, stream>>>(wo, wo, wo, 4096, 4096, att, out, 4096,
                                     0, 1.0f);
}

// Round 6
// 247.335 us; speedup vs baseline: 1.1036x; 1.1036x over previous
//
#include <hip/hip_runtime.h>
#include <hip/hip_bf16.h>
#include <cstdint>
#include <cstddef>

#define DIM 4096
#define NB 16
#define NH 32
#define NKV 8
#define HD 128
#define PREFIX 8192
#define KPB 256                   // keys per block
#define KPW 64                    // keys per wave
#define NCH (PREFIX / KPB)        // 32 key-chunks per batch
#define NPART NCH                 // 32 merged partials per (b, head)

// workspace layout (in floats)
#define WS_QKV 0                                   // [16][6144] q|k_new|v_new
#define WS_ATT (WS_QKV + NB * 6144)                // [16][4096] attn output
#define WS_ML  (WS_ATT + NB * DIM)                 // [512 blocks][32 gh][2]
#define WS_OP  (WS_ML + NB * NCH * 32 * 2)         // [512 blocks][32 gh][128]

// Non-temporal (streaming) loads: read-once data should not allocate in L2.
typedef float f4_t __attribute__((ext_vector_type(4)));
typedef float f2_t __attribute__((ext_vector_type(2)));
__device__ __forceinline__ float4 ntload4(const float* p) {
  f4_t v = __builtin_nontemporal_load((const f4_t*)p);
  return make_float4(v.x, v.y, v.z, v.w);
}
__device__ __forceinline__ float2 ntload2(const float* p) {
  f2_t v = __builtin_nontemporal_load((const f2_t*)p);
  return make_float2(v.x, v.y);
}

// ---------------------------------------------------------------------------
// Batched GEMV: Y[b][row] = sum_d X[b][d] * W[row][d], B=16, D=4096.
// W = concat of up to three row-major matrices (boundaries b1,b2).
// NW waves per block; each wave owns 4 rows x 16 batches. x staged in two
// 2048-dim chunks (128 KB LDS) -> only 2 barrier pairs per block.
// Weight rows are read exactly once -> non-temporal.
// ---------------------------------------------------------------------------
template <int NW>
__global__ __launch_bounds__(NW * 64) void gemv16(
    const float* __restrict__ W0, const float* __restrict__ W1,
    const float* __restrict__ W2, int b1, int b2,
    const float* __restrict__ X, float* __restrict__ Y,
    int y_stride, int scale_rows, float scale) {
  __shared__ float xs[NB][2048];  // 128 KB
  const int tid = threadIdx.x;
  const int wave = tid >> 6, lane = tid & 63;
  const int row_base = blockIdx.x * (NW * 4) + wave * 4;

  const float* Wp;
  if (row_base < b1)       Wp = W0 + (size_t)row_base * DIM;
  else if (row_base < b2)  Wp = W1 + (size_t)(row_base - b1) * DIM;
  else                     Wp = W2 + (size_t)(row_base - b2) * DIM;

  float acc[4][NB];
#pragma unroll
  for (int r = 0; r < 4; ++r)
#pragma unroll
    for (int b = 0; b < NB; ++b) acc[r][b] = 0.0f;

  for (int k0 = 0; k0 < DIM; k0 += 2048) {
    __syncthreads();
#pragma unroll
    for (int i = 0; i < (8192 + NW * 64 - 1) / (NW * 64); ++i) {
      const int idx = tid + i * (NW * 64);
      if (idx < 8192) {
        const int b = idx >> 9, c = idx & 511;
        ((float4*)&xs[b][0])[c] =
            ((const float4*)(X + (size_t)b * DIM + k0))[c];
      }
    }
    __syncthreads();
#pragma unroll 4
    for (int ii = 0; ii < 8; ++ii) {
      const int d = ii * 256 + lane * 4;
      float4 w4[4];
#pragma unroll
      for (int r = 0; r < 4; ++r)
        w4[r] = ntload4(Wp + (size_t)r * DIM + k0 + d);
#pragma unroll
      for (int b = 0; b < NB; ++b) {
        float4 x4 = *(const float4*)&xs[b][d];
#pragma unroll
        for (int r = 0; r < 4; ++r)
          acc[r][b] += w4[r].x * x4.x + w4[r].y * x4.y +
                       w4[r].z * x4.z + w4[r].w * x4.w;
      }
    }
  }

#pragma unroll
  for (int r = 0; r < 4; ++r)
#pragma unroll
    for (int b = 0; b < NB; ++b) {
      float v = acc[r][b];
#pragma unroll
      for (int m = 1; m < 64; m <<= 1) v += __shfl_xor(v, m);
      acc[r][b] = v;
    }
  const int rsel = lane >> 4, bsel = lane & 15;
  float v = 0.0f;
#pragma unroll
  for (int r = 0; r < 4; ++r)
#pragma unroll
    for (int b = 0; b < NB; ++b)
      if (r == rsel && b == bsel) v = acc[r][b];  // compile-time indices only
  const int row = row_base + rsel;
  if (row < scale_rows) v *= scale;
  Y[(size_t)bsel * y_stride + row] = v;
}

// ---------------------------------------------------------------------------
// Row-contiguous flash-decoding partial. Block = (b, 256-key range) covering
// ALL 8 kv-heads; wave owns 64 keys and streams K rows (4 KB each) fully
// sequentially: lane l -> section g=l>>3, dims (l&7)*4 + j*32. Scores for all
// 32 (g,h) pairs; wave-local softmax; PV with identical mapping; in-block
// merge of the 4 wave-partials (2 barriers). K/V loads are non-temporal
// (read exactly once).
// ---------------------------------------------------------------------------
__global__ __launch_bounds__(256, 2) void attn_partial(
    const float* __restrict__ K, const float* __restrict__ V,
    const float* __restrict__ qkv, float* __restrict__ opart,
    float* __restrict__ mlpart) {
  __shared__ float lds[4 * 32 * 132];  // 67.6 KB: scores, then merge buffer
  __shared__ float mw[4][32], lw[4][32];
  const int tid = threadIdx.x, wave = tid >> 6, lane = tid & 63;
  const int g = lane >> 3, soff = lane & 7;
  const int bid = blockIdx.x;
  const int c = bid & (NCH - 1), b = bid >> 5;

  float* scw = lds + wave * (KPW * 32);  // per-wave scores [64 keys][32 gh]

  // q fragments: qreg[hh][j] = q[g*4+hh][j*32 + soff*4 .. +3] (pre-scaled)
  float4 qreg[4][4];
#pragma unroll
  for (int hh = 0; hh < 4; ++hh)
#pragma unroll
    for (int j = 0; j < 4; ++j)
      qreg[hh][j] = *(const float4*)(qkv + (size_t)b * 6144 +
                                     (g * 4 + hh) * HD + j * 32 + soff * 4);

  const size_t rowbase = ((size_t)b * PREFIX + c * KPB + wave * KPW) *
                         (NKV * HD);
  const float* kp = K + rowbase + g * HD + soff * 4;

  // ---- scoring: 64 sequential 4 KB rows per wave ----
  float mreg[4] = {-1e30f, -1e30f, -1e30f, -1e30f};
#pragma unroll 2
  for (int k = 0; k < KPW; ++k) {
    float4 k4[4];
#pragma unroll
    for (int j = 0; j < 4; ++j)
      k4[j] = ntload4(kp + (size_t)k * (NKV * HD) + j * 32);
    float p[4] = {0.f, 0.f, 0.f, 0.f};
#pragma unroll
    for (int j = 0; j < 4; ++j)
#pragma unroll
      for (int hh = 0; hh < 4; ++hh)
        p[hh] += qreg[hh][j].x * k4[j].x + qreg[hh][j].y * k4[j].y +
                 qreg[hh][j].z * k4[j].z + qreg[hh][j].w * k4[j].w;
    // reduce over the 8 lanes of this section (allreduce butterfly)
#pragma unroll
    for (int mk = 1; mk < 8; mk <<= 1) {
      p[0] += __shfl_xor(p[0], mk);
      p[1] += __shfl_xor(p[1], mk);
      p[2] += __shfl_xor(p[2], mk);
      p[3] += __shfl_xor(p[3], mk);
    }
#pragma unroll
    for (int hh = 0; hh < 4; ++hh) mreg[hh] = fmaxf(mreg[hh], p[hh]);
    float wv = p[0];
    wv = (soff == 1) ? p[1] : wv;
    wv = (soff == 2) ? p[2] : wv;
    wv = (soff == 3) ? p[3] : wv;
    if (soff < 4) scw[k * 32 + g * 4 + soff] = wv;  // banks distinct
  }
  {
    float mv = mreg[0];
    mv = (soff == 1) ? mreg[1] : mv;
    mv = (soff == 2) ? mreg[2] : mv;
    mv = (soff == 3) ? mreg[3] : mv;
    if (soff < 4) mw[wave][g * 4 + soff] = mv;
  }
  asm volatile("s_waitcnt lgkmcnt(0)" ::: "memory");
  __builtin_amdgcn_sched_barrier(0);

  // ---- exp pass: lane pair per gh; accumulate l ----
  {
    const int gh = lane >> 1, half = lane & 1;
    const float m = mw[wave][gh];
    float lsum = 0.f;
#pragma unroll 8
    for (int i = 0; i < 32; ++i) {
      const int idx = (half * 32 + i) * 32 + gh;
      const float pe = __expf(scw[idx] - m);
      scw[idx] = pe;
      lsum += pe;
    }
    lsum += __shfl_xor(lsum, 1);
    if (half == 0) lw[wave][gh] = lsum;
  }
  asm volatile("s_waitcnt lgkmcnt(0)" ::: "memory");
  __builtin_amdgcn_sched_barrier(0);

  // ---- PV: same contiguous mapping over V ----
  const float* vp = V + rowbase + g * HD + soff * 4;
  float4 acc[4][4];
#pragma unroll
  for (int hh = 0; hh < 4; ++hh)
#pragma unroll
    for (int j = 0; j < 4; ++j) acc[hh][j] = make_float4(0.f, 0.f, 0.f, 0.f);
#pragma unroll 2
  for (int k = 0; k < KPW; ++k) {
    float4 v4[4];
#pragma unroll
    for (int j = 0; j < 4; ++j)
      v4[j] = ntload4(vp + (size_t)k * (NKV * HD) + j * 32);
    float pr[4];
#pragma unroll
    for (int hh = 0; hh < 4; ++hh) pr[hh] = scw[k * 32 + g * 4 + hh];
#pragma unroll
    for (int hh = 0; hh < 4; ++hh)
#pragma unroll
      for (int j = 0; j < 4; ++j) {
        acc[hh][j].x += pr[hh] * v4[j].x;
        acc[hh][j].y += pr[hh] * v4[j].y;
        acc[hh][j].z += pr[hh] * v4[j].z;
        acc[hh][j].w += pr[hh] * v4[j].w;
      }
  }

  // ---- in-block merge of the 4 wave-partials ----
  __syncthreads();  // all PV reads of scw done before overwrite
  float* mb = lds + wave * (32 * 132);
#pragma unroll
  for (int hh = 0; hh < 4; ++hh)
#pragma unroll
    for (int j = 0; j < 4; ++j)
      *(float4*)(mb + (g * 4 + hh) * 132 + j * 32 + soff * 4) = acc[hh][j];
  __syncthreads();
  {
    const int gh = tid >> 3, sub = tid & 7;
    const float m0 = mw[0][gh], m1 = mw[1][gh], m2 = mw[2][gh], m3 = mw[3][gh];
    const float M = fmaxf(fmaxf(m0, m1), fmaxf(m2, m3));
    const float w0 = __expf(m0 - M), w1 = __expf(m1 - M);
    const float w2 = __expf(m2 - M), w3 = __expf(m3 - M);
    const float L = w0 * lw[0][gh] + w1 * lw[1][gh] +
                    w2 * lw[2][gh] + w3 * lw[3][gh];
    const size_t obase = ((size_t)bid * 32 + gh) * HD;
#pragma unroll
    for (int i = 0; i < 4; ++i) {
      const int d = sub * 16 + i * 4;
      float4 a0 = *(const float4*)(lds + 0 * 4224 + gh * 132 + d);
      float4 a1 = *(const float4*)(lds + 1 * 4224 + gh * 132 + d);
      float4 a2 = *(const float4*)(lds + 2 * 4224 + gh * 132 + d);
      float4 a3 = *(const float4*)(lds + 3 * 4224 + gh * 132 + d);
      float4 o;
      o.x = w0 * a0.x + w1 * a1.x + w2 * a2.x + w3 * a3.x;
      o.y = w0 * a0.y + w1 * a1.y + w2 * a2.y + w3 * a3.y;
      o.z = w0 * a0.z + w1 * a1.z + w2 * a2.z + w3 * a3.z;
      o.w = w0 * a0.w + w1 * a1.w + w2 * a2.w + w3 * a3.w;
      *(float4*)(opart + obase + d) = o;
    }
    if (sub == 0)
      *(float2*)(mlpart + ((size_t)bid * 32 + gh) * 2) = make_float2(M, L);
  }
}

// ---------------------------------------------------------------------------
// Combine the 32 chunk-partials per (b, head) AND fold in the new token
// analytically (its score is a single 128-dim dot). One wave per (b,h).
// ---------------------------------------------------------------------------
__global__ __launch_bounds__(64) void combine(
    const float* __restrict__ opart, const float* __restrict__ mlpart,
    const float* __restrict__ qkv, float* __restrict__ aout) {
  const int bh = blockIdx.x;  // b*32 + hg
  const int hg = bh & 31, b = bh >> 5;
  const int g = hg >> 2;
  const int lane = threadIdx.x;

  // new-token score: q (already scaled) . k_new
  const float* qp = qkv + (size_t)b * 6144 + hg * HD;
  const float* kn = qkv + (size_t)b * 6144 + 4096 + g * HD;
  const float* vn = qkv + (size_t)b * 6144 + 5120 + g * HD;
  float2 q2 = *(const float2*)(qp + lane * 2);
  float2 k2 = *(const float2*)(kn + lane * 2);
  float sn = q2.x * k2.x + q2.y * k2.y;
#pragma unroll
  for (int mk = 1; mk < 64; mk <<= 1) sn += __shfl_xor(sn, mk);

  float M = sn;
#pragma unroll 8
  for (int c = 0; c < NPART; ++c)
    M = fmaxf(M, mlpart[((size_t)(b * NCH + c) * 32 + hg) * 2]);

  float L = 0, ax = 0, ay = 0;
#pragma unroll 8
  for (int c = 0; c < NPART; ++c) {
    const size_t pidx = (size_t)(b * NCH + c) * 32 + hg;
    const float mc = mlpart[pidx * 2 + 0];
    const float lc = mlpart[pidx * 2 + 1];
    const float w = __expf(mc - M);
    L += lc * w;
    float2 o2 = ntload2(opart + pidx * HD + lane * 2);
    ax += w * o2.x;
    ay += w * o2.y;
  }
  const float pn = __expf(sn - M);
  float2 v2 = *(const float2*)(vn + lane * 2);
  L += pn;
  ax += pn * v2.x;
  ay += pn * v2.y;

  const float inv = 1.0f / L;
  aout[(size_t)b * DIM + hg * HD + lane * 2 + 0] = ax * inv;
  aout[(size_t)b * DIM + hg * HD + lane * 2 + 1] = ay * inv;
}

// ---------------------------------------------------------------------------
extern "C" void kernel_launch(void* const* d_in, const int* in_sizes, int n_in,
                              void* d_out, int out_size, void* d_ws,
                              size_t ws_size, hipStream_t stream) {
  const float* x  = (const float*)d_in[0];
  const float* ck = (const float*)d_in[1];
  const float* cv = (const float*)d_in[2];
  const float* wq = (const float*)d_in[3];
  const float* wk = (const float*)d_in[4];
  const float* wv = (const float*)d_in[5];
  const float* wo = (const float*)d_in[6];
  float* out = (float*)d_out;
  float* ws = (float*)d_ws;

  float* qkv = ws + WS_QKV;
  float* att = ws + WS_ATT;
  float* ml  = ws + WS_ML;
  float* op  = ws + WS_OP;

  const float scale = 0.08838834764831845f;  // 1/sqrt(128)

  // 1) fused q/k_new/v_new projection: 6144 rows = 24 rows x 256 blocks
  gemv16<6><<<256, 384, 0, stream>>>(wq, wk, wv, 4096, 5120, x, qkv, 6144,
                                     4096, scale);
  // 2) row-contiguous flash partials: 512 blocks (2/CU), all heads per block
  attn_partial<<<NB * NCH, 256, 0, stream>>>(ck, cv, qkv, op, ml);
  // 3) merge 32 partials per (b,h) + new token
  combine<<<NB * NH, 64, 0, stream>>>(op, ml, qkv, att);
  // 4) output projection: 4096 rows = 16 rows x 256 blocks
  gemv16<4><<<256, 256, 0, stream>>>(wo, wo, wo, 4096, 4096, att, out, 4096,
                                     0, 1.0f);
}

// Round 7
// 244.440 us; speedup vs baseline: 1.1166x; 1.0118x over previous
//
#include <hip/hip_runtime.h>
#include <hip/hip_bf16.h>
#include <cstdint>
#include <cstddef>

#define DIM 4096
#define NB 16
#define NH 32
#define NKV 8
#define HD 128
#define PREFIX 8192
#define KPB 256                   // keys per block
#define KPW 64                    // keys per wave
#define NCH (PREFIX / KPB)        // 32 key-chunks per batch
#define NPART NCH                 // 32 merged partials per (b, head)

// workspace layout (in floats)
#define WS_QKV 0                                   // [16][6144] q|k_new|v_new
#define WS_ATT (WS_QKV + NB * 6144)                // [16][4096] attn output
#define WS_ML  (WS_ATT + NB * DIM)                 // [512 blocks][32 gh][2]
#define WS_OP  (WS_ML + NB * NCH * 32 * 2)         // [512 blocks][32 gh][128]

// Non-temporal (streaming) loads: read-once data should not allocate in L2.
typedef float f4_t __attribute__((ext_vector_type(4)));
typedef float f2_t __attribute__((ext_vector_type(2)));
__device__ __forceinline__ float4 ntload4(const float* p) {
  f4_t v = __builtin_nontemporal_load((const f4_t*)p);
  return make_float4(v.x, v.y, v.z, v.w);
}
__device__ __forceinline__ float2 ntload2(const float* p) {
  f2_t v = __builtin_nontemporal_load((const f2_t*)p);
  return make_float2(v.x, v.y);
}

// ---------------------------------------------------------------------------
// Batched GEMV: Y[b][row] = sum_d X[b][d] * W[row][d], B=16, D=4096.
// W = concat of up to three row-major matrices (boundaries b1,b2).
// NW waves per block; each wave owns 4 rows x 16 batches. x staged in two
// 2048-dim chunks (128 KB LDS) -> only 2 barrier pairs per block.
// Weight rows are read exactly once -> non-temporal.
// ---------------------------------------------------------------------------
template <int NW>
__global__ __launch_bounds__(NW * 64) void gemv16(
    const float* __restrict__ W0, const float* __restrict__ W1,
    const float* __restrict__ W2, int b1, int b2,
    const float* __restrict__ X, float* __restrict__ Y,
    int y_stride, int scale_rows, float scale) {
  __shared__ float xs[NB][2048];  // 128 KB
  const int tid = threadIdx.x;
  const int wave = tid >> 6, lane = tid & 63;
  const int row_base = blockIdx.x * (NW * 4) + wave * 4;

  const float* Wp;
  if (row_base < b1)       Wp = W0 + (size_t)row_base * DIM;
  else if (row_base < b2)  Wp = W1 + (size_t)(row_base - b1) * DIM;
  else                     Wp = W2 + (size_t)(row_base - b2) * DIM;

  float acc[4][NB];
#pragma unroll
  for (int r = 0; r < 4; ++r)
#pragma unroll
    for (int b = 0; b < NB; ++b) acc[r][b] = 0.0f;

  for (int k0 = 0; k0 < DIM; k0 += 2048) {
    __syncthreads();
#pragma unroll
    for (int i = 0; i < (8192 + NW * 64 - 1) / (NW * 64); ++i) {
      const int idx = tid + i * (NW * 64);
      if (idx < 8192) {
        const int b = idx >> 9, c = idx & 511;
        ((float4*)&xs[b][0])[c] =
            ((const float4*)(X + (size_t)b * DIM + k0))[c];
      }
    }
    __syncthreads();
#pragma unroll 4
    for (int ii = 0; ii < 8; ++ii) {
      const int d = ii * 256 + lane * 4;
      float4 w4[4];
#pragma unroll
      for (int r = 0; r < 4; ++r)
        w4[r] = ntload4(Wp + (size_t)r * DIM + k0 + d);
#pragma unroll
      for (int b = 0; b < NB; ++b) {
        float4 x4 = *(const float4*)&xs[b][d];
#pragma unroll
        for (int r = 0; r < 4; ++r)
          acc[r][b] += w4[r].x * x4.x + w4[r].y * x4.y +
                       w4[r].z * x4.z + w4[r].w * x4.w;
      }
    }
  }

#pragma unroll
  for (int r = 0; r < 4; ++r)
#pragma unroll
    for (int b = 0; b < NB; ++b) {
      float v = acc[r][b];
#pragma unroll
      for (int m = 1; m < 64; m <<= 1) v += __shfl_xor(v, m);
      acc[r][b] = v;
    }
  const int rsel = lane >> 4, bsel = lane & 15;
  float v = 0.0f;
#pragma unroll
  for (int r = 0; r < 4; ++r)
#pragma unroll
    for (int b = 0; b < NB; ++b)
      if (r == rsel && b == bsel) v = acc[r][b];  // compile-time indices only
  const int row = row_base + rsel;
  if (row < scale_rows) v *= scale;
  Y[(size_t)bsel * y_stride + row] = v;
}

// ---------------------------------------------------------------------------
// Row-contiguous flash-decoding partial, 4-key-deep load batching.
// Block = (b, 256-key range) covering ALL 8 kv-heads; wave owns 64 keys,
// streams K rows (4 KB each) sequentially: lane l -> section g=l>>3,
// dims (l&7)*4 + j*32. Per batch: issue 16 NT loads (4 keys), then compute.
// Wave-local softmax; PV identically batched; in-block merge (2 barriers).
// ---------------------------------------------------------------------------
__global__ __launch_bounds__(256, 2) void attn_partial(
    const float* __restrict__ K, const float* __restrict__ V,
    const float* __restrict__ qkv, float* __restrict__ opart,
    float* __restrict__ mlpart) {
  __shared__ float lds[4 * 32 * 132];  // 67.6 KB: scores, then merge buffer
  __shared__ float mw[4][32], lw[4][32];
  const int tid = threadIdx.x, wave = tid >> 6, lane = tid & 63;
  const int g = lane >> 3, soff = lane & 7;
  const int bid = blockIdx.x;
  const int c = bid & (NCH - 1), b = bid >> 5;

  float* scw = lds + wave * (KPW * 32);  // per-wave scores [64 keys][32 gh]

  // q fragments: qreg[hh][j] = q[g*4+hh][j*32 + soff*4 .. +3] (pre-scaled)
  float4 qreg[4][4];
#pragma unroll
  for (int hh = 0; hh < 4; ++hh)
#pragma unroll
    for (int j = 0; j < 4; ++j)
      qreg[hh][j] = *(const float4*)(qkv + (size_t)b * 6144 +
                                     (g * 4 + hh) * HD + j * 32 + soff * 4);

  const size_t rowbase = ((size_t)b * PREFIX + c * KPB + wave * KPW) *
                         (NKV * HD);
  const float* kp = K + rowbase + g * HD + soff * 4;

  // ---- scoring: 16 batches of 4 keys; 16 loads in flight per batch ----
  float mreg[4] = {-1e30f, -1e30f, -1e30f, -1e30f};
  for (int kb = 0; kb < KPW / 4; ++kb) {
    float4 k4[4][4];
#pragma unroll
    for (int kk = 0; kk < 4; ++kk)
#pragma unroll
      for (int j = 0; j < 4; ++j)
        k4[kk][j] =
            ntload4(kp + (size_t)(kb * 4 + kk) * (NKV * HD) + j * 32);
#pragma unroll
    for (int kk = 0; kk < 4; ++kk) {
      float p[4] = {0.f, 0.f, 0.f, 0.f};
#pragma unroll
      for (int j = 0; j < 4; ++j)
#pragma unroll
        for (int hh = 0; hh < 4; ++hh)
          p[hh] += qreg[hh][j].x * k4[kk][j].x + qreg[hh][j].y * k4[kk][j].y +
                   qreg[hh][j].z * k4[kk][j].z + qreg[hh][j].w * k4[kk][j].w;
      // reduce over the 8 lanes of this section (allreduce butterfly)
#pragma unroll
      for (int mk = 1; mk < 8; mk <<= 1) {
        p[0] += __shfl_xor(p[0], mk);
        p[1] += __shfl_xor(p[1], mk);
        p[2] += __shfl_xor(p[2], mk);
        p[3] += __shfl_xor(p[3], mk);
      }
#pragma unroll
      for (int hh = 0; hh < 4; ++hh) mreg[hh] = fmaxf(mreg[hh], p[hh]);
      float wv = p[0];
      wv = (soff == 1) ? p[1] : wv;
      wv = (soff == 2) ? p[2] : wv;
      wv = (soff == 3) ? p[3] : wv;
      if (soff < 4) scw[(kb * 4 + kk) * 32 + g * 4 + soff] = wv;
    }
  }
  {
    float mv = mreg[0];
    mv = (soff == 1) ? mreg[1] : mv;
    mv = (soff == 2) ? mreg[2] : mv;
    mv = (soff == 3) ? mreg[3] : mv;
    if (soff < 4) mw[wave][g * 4 + soff] = mv;
  }
  asm volatile("s_waitcnt lgkmcnt(0)" ::: "memory");
  __builtin_amdgcn_sched_barrier(0);

  // ---- exp pass: lane pair per gh; accumulate l ----
  {
    const int gh = lane >> 1, half = lane & 1;
    const float m = mw[wave][gh];
    float lsum = 0.f;
#pragma unroll 8
    for (int i = 0; i < 32; ++i) {
      const int idx = (half * 32 + i) * 32 + gh;
      const float pe = __expf(scw[idx] - m);
      scw[idx] = pe;
      lsum += pe;
    }
    lsum += __shfl_xor(lsum, 1);
    if (half == 0) lw[wave][gh] = lsum;
  }
  asm volatile("s_waitcnt lgkmcnt(0)" ::: "memory");
  __builtin_amdgcn_sched_barrier(0);

  // ---- PV: 4-key batches over V with the same contiguous mapping ----
  const float* vp = V + rowbase + g * HD + soff * 4;
  float4 acc[4][4];
#pragma unroll
  for (int hh = 0; hh < 4; ++hh)
#pragma unroll
    for (int j = 0; j < 4; ++j) acc[hh][j] = make_float4(0.f, 0.f, 0.f, 0.f);
  for (int kb = 0; kb < KPW / 4; ++kb) {
    float4 v4[4][4];
#pragma unroll
    for (int kk = 0; kk < 4; ++kk)
#pragma unroll
      for (int j = 0; j < 4; ++j)
        v4[kk][j] =
            ntload4(vp + (size_t)(kb * 4 + kk) * (NKV * HD) + j * 32);
#pragma unroll
    for (int kk = 0; kk < 4; ++kk) {
      // all heads' p for this key in one ds_read_b128 (broadcast per g)
      float4 pr = *(const float4*)&scw[(kb * 4 + kk) * 32 + g * 4];
      const float prh[4] = {pr.x, pr.y, pr.z, pr.w};
#pragma unroll
      for (int hh = 0; hh < 4; ++hh)
#pragma unroll
        for (int j = 0; j < 4; ++j) {
          acc[hh][j].x += prh[hh] * v4[kk][j].x;
          acc[hh][j].y += prh[hh] * v4[kk][j].y;
          acc[hh][j].z += prh[hh] * v4[kk][j].z;
          acc[hh][j].w += prh[hh] * v4[kk][j].w;
        }
    }
  }

  // ---- in-block merge of the 4 wave-partials ----
  __syncthreads();  // all PV reads of scw done before overwrite
  float* mb = lds + wave * (32 * 132);
#pragma unroll
  for (int hh = 0; hh < 4; ++hh)
#pragma unroll
    for (int j = 0; j < 4; ++j)
      *(float4*)(mb + (g * 4 + hh) * 132 + j * 32 + soff * 4) = acc[hh][j];
  __syncthreads();
  {
    const int gh = tid >> 3, sub = tid & 7;
    const float m0 = mw[0][gh], m1 = mw[1][gh], m2 = mw[2][gh], m3 = mw[3][gh];
    const float M = fmaxf(fmaxf(m0, m1), fmaxf(m2, m3));
    const float w0 = __expf(m0 - M), w1 = __expf(m1 - M);
    const float w2 = __expf(m2 - M), w3 = __expf(m3 - M);
    const float L = w0 * lw[0][gh] + w1 * lw[1][gh] +
                    w2 * lw[2][gh] + w3 * lw[3][gh];
    const size_t obase = ((size_t)bid * 32 + gh) * HD;
#pragma unroll
    for (int i = 0; i < 4; ++i) {
      const int d = sub * 16 + i * 4;
      float4 a0 = *(const float4*)(lds + 0 * 4224 + gh * 132 + d);
      float4 a1 = *(const float4*)(lds + 1 * 4224 + gh * 132 + d);
      float4 a2 = *(const float4*)(lds + 2 * 4224 + gh * 132 + d);
      float4 a3 = *(const float4*)(lds + 3 * 4224 + gh * 132 + d);
      float4 o;
      o.x = w0 * a0.x + w1 * a1.x + w2 * a2.x + w3 * a3.x;
      o.y = w0 * a0.y + w1 * a1.y + w2 * a2.y + w3 * a3.y;
      o.z = w0 * a0.z + w1 * a1.z + w2 * a2.z + w3 * a3.z;
      o.w = w0 * a0.w + w1 * a1.w + w2 * a2.w + w3 * a3.w;
      *(float4*)(opart + obase + d) = o;
    }
    if (sub == 0)
      *(float2*)(mlpart + ((size_t)bid * 32 + gh) * 2) = make_float2(M, L);
  }
}

// ---------------------------------------------------------------------------
// Combine the 32 chunk-partials per (b, head) AND fold in the new token
// analytically (its score is a single 128-dim dot). One wave per (b,h).
// ---------------------------------------------------------------------------
__global__ __launch_bounds__(64) void combine(
    const float* __restrict__ opart, const float* __restrict__ mlpart,
    const float* __restrict__ qkv, float* __restrict__ aout) {
  const int bh = blockIdx.x;  // b*32 + hg
  const int hg = bh & 31, b = bh >> 5;
  const int g = hg >> 2;
  const int lane = threadIdx.x;

  // new-token score: q (already scaled) . k_new
  const float* qp = qkv + (size_t)b * 6144 + hg * HD;
  const float* kn = qkv + (size_t)b * 6144 + 4096 + g * HD;
  const float* vn = qkv + (size_t)b * 6144 + 5120 + g * HD;
  float2 q2 = *(const float2*)(qp + lane * 2);
  float2 k2 = *(const float2*)(kn + lane * 2);
  float sn = q2.x * k2.x + q2.y * k2.y;
#pragma unroll
  for (int mk = 1; mk < 64; mk <<= 1) sn += __shfl_xor(sn, mk);

  float M = sn;
#pragma unroll 8
  for (int c = 0; c < NPART; ++c)
    M = fmaxf(M, mlpart[((size_t)(b * NCH + c) * 32 + hg) * 2]);

  float L = 0, ax = 0, ay = 0;
#pragma unroll 8
  for (int c = 0; c < NPART; ++c) {
    const size_t pidx = (size_t)(b * NCH + c) * 32 + hg;
    const float mc = mlpart[pidx * 2 + 0];
    const float lc = mlpart[pidx * 2 + 1];
    const float w = __expf(mc - M);
    L += lc * w;
    float2 o2 = ntload2(opart + pidx * HD + lane * 2);
    ax += w * o2.x;
    ay += w * o2.y;
  }
  const float pn = __expf(sn - M);
  float2 v2 = *(const float2*)(vn + lane * 2);
  L += pn;
  ax += pn * v2.x;
  ay += pn * v2.y;

  const float inv = 1.0f / L;
  aout[(size_t)b * DIM + hg * HD + lane * 2 + 0] = ax * inv;
  aout[(size_t)b * DIM + hg * HD + lane * 2 + 1] = ay * inv;
}

// ---------------------------------------------------------------------------
extern "C" void kernel_launch(void* const* d_in, const int* in_sizes, int n_in,
                              void* d_out, int out_size, void* d_ws,
                              size_t ws_size, hipStream_t stream) {
  const float* x  = (const float*)d_in[0];
  const float* ck = (const float*)d_in[1];
  const float* cv = (const float*)d_in[2];
  const float* wq = (const float*)d_in[3];
  const float* wk = (const float*)d_in[4];
  const float* wv = (const float*)d_in[5];
  const float* wo = (const float*)d_in[6];
  float* out = (float*)d_out;
  float* ws = (float*)d_ws;

  float* qkv = ws + WS_QKV;
  float* att = ws + WS_ATT;
  float* ml  = ws + WS_ML;
  float* op  = ws + WS_OP;

  const float scale = 0.08838834764831845f;  // 1/sqrt(128)

  // 1) fused q/k_new/v_new projection: 6144 rows = 24 rows x 256 blocks
  gemv16<6><<<256, 384, 0, stream>>>(wq, wk, wv, 4096, 5120, x, qkv, 6144,
                                     4096, scale);
  // 2) row-contiguous flash partials: 512 blocks (2/CU), all heads per block
  attn_partial<<<NB * NCH, 256, 0, stream>>>(ck, cv, qkv, op, ml);
  // 3) merge 32 partials per (b,h) + new token
  combine<<<NB * NH, 64, 0, stream>>>(op, ml, qkv, att);
  // 4) output projection: 4096 rows = 16 rows x 256 blocks
  gemv16<4><<<256, 256, 0, stream>>>(wo, wo, wo, 4096, 4096, att, out, 4096,
                                     0, 1.0f);
}